// Round 1
// baseline (2510.377 us; speedup 1.0000x reference)
//
#include <hip/hip_runtime.h>

// Detect whether neighbor_indices is int64 or int32.
// If int64 (values are atom ids < 2^31), every odd 32-bit word (the high
// halves) is zero. For genuine random int32 indices in [0,100000), the OR of
// 1024 odd words is nonzero with overwhelming probability.
__global__ void detect_idx64_kernel(const unsigned int* __restrict__ idx_u32,
                                    int* __restrict__ flag) {
    __shared__ int nonzero;
    if (threadIdx.x == 0) nonzero = 0;
    __syncthreads();
    unsigned int v = idx_u32[2 * (threadIdx.x +   0) + 1]
                   | idx_u32[2 * (threadIdx.x + 256) + 1]
                   | idx_u32[2 * (threadIdx.x + 512) + 1]
                   | idx_u32[2 * (threadIdx.x + 768) + 1];
    if (v != 0u) atomicAdd(&nonzero, 1);
    __syncthreads();
    if (threadIdx.x == 0) *flag = (nonzero == 0) ? 1 : 0;  // 1 => int64
}

__global__ __launch_bounds__(256) void edge_scatter_kernel(
    const float4* __restrict__ charges,     // [N_ATOMS] rows of 4 floats
    const void*  __restrict__ idx,          // [N_EDGES][2] int32 or int64
    const float* __restrict__ dist,         // [N_EDGES]
    float*       __restrict__ out,          // [N_ATOMS*4], pre-zeroed
    const int*   __restrict__ flag64,
    int n_edges)
{
    int e = blockIdx.x * blockDim.x + threadIdx.x;
    if (e >= n_edges) return;

    int ai, aj;
    if (*flag64) {
        const longlong2* p = (const longlong2*)idx;
        longlong2 v = p[e];                 // 16B coalesced
        ai = (int)v.x; aj = (int)v.y;
    } else {
        const int2* p = (const int2*)idx;
        int2 v = p[e];                      // 8B coalesced
        ai = v.x; aj = v.y;
    }

    float d = dist[e];
    // erfc(d / (sqrt(2)*SMEARING)) / d, with the final /2 folded in.
    float pot = 0.5f * erfcf(d * 0.70710678118654752440f) / d;

    float4 ci = charges[ai];                // L2/L3-resident gathers
    float4 cj = charges[aj];

    float* oi = out + (size_t)ai * 4;
    float* oj = out + (size_t)aj * 4;
    unsafeAtomicAdd(oi + 0, cj.x * pot);
    unsafeAtomicAdd(oi + 1, cj.y * pot);
    unsafeAtomicAdd(oi + 2, cj.z * pot);
    unsafeAtomicAdd(oi + 3, cj.w * pot);
    unsafeAtomicAdd(oj + 0, ci.x * pot);
    unsafeAtomicAdd(oj + 1, ci.y * pot);
    unsafeAtomicAdd(oj + 2, ci.z * pot);
    unsafeAtomicAdd(oj + 3, ci.w * pot);
}

extern "C" void kernel_launch(void* const* d_in, const int* in_sizes, int n_in,
                              void* d_out, int out_size, void* d_ws, size_t ws_size,
                              hipStream_t stream) {
    const float4* charges = (const float4*)d_in[0];
    const void*   idx     = d_in[1];
    const float*  dist    = (const float*)d_in[2];
    float*        out     = (float*)d_out;
    int n_edges = in_sizes[2];              // == N_EDGES (distances count)
    int* flag = (int*)d_ws;

    hipMemsetAsync(d_out, 0, (size_t)out_size * sizeof(float), stream);
    detect_idx64_kernel<<<1, 256, 0, stream>>>((const unsigned int*)idx, flag);

    int blocks = (n_edges + 255) / 256;
    edge_scatter_kernel<<<blocks, 256, 0, stream>>>(charges, idx, dist, out,
                                                    flag, n_edges);
}